// Round 12
// baseline (372.380 us; speedup 1.0000x reference)
//
#include <hip/hip_runtime.h>
#include <math.h>

typedef _Float16 half8 __attribute__((ext_vector_type(8)));
typedef _Float16 half4 __attribute__((ext_vector_type(4)));
typedef float f32x4 __attribute__((ext_vector_type(4)));

constexpr int IN    = 256;
constexpr int NCLS  = 47;
constexpr int HD1   = 188;
constexpr float NEG_SLOPE = 0.2f;
constexpr int ND0 = 50000, ND1 = 10000;

static __device__ __forceinline__ float leaky(float x) {
    return x >= 0.f ? x : NEG_SLOPE * x;
}

__device__ __forceinline__ void gload16(const void* g, void* l) {
    __builtin_amdgcn_global_load_lds((const __attribute__((address_space(1))) void*)g,
                                     (__attribute__((address_space(3))) void*)l, 16, 0, 0);
}

// ---------------- prep: per-head pre-swizzled weight planes + folded attn vectors ----
// swz(k,n) = (((k>>3) ^ (n&31)) & 31)<<3 | (k&7)
__global__ __launch_bounds__(256) void prep_k(
        const float* __restrict__ W0s, const float* __restrict__ W1s,
        const float* __restrict__ W0d, const float* __restrict__ W1d,
        const float* __restrict__ al0, const float* __restrict__ ar0,
        const float* __restrict__ al1, const float* __restrict__ ar1,
        _Float16* __restrict__ B0p, _Float16* __restrict__ B1p,
        float* __restrict__ vl0T, float* __restrict__ vr0T,
        float* __restrict__ vl1T, float* __restrict__ vr1T) {
    int b = blockIdx.x, t = threadIdx.x;
    if (b < 256) {                 // B0p[h][n(64)][swz k]  <- W0s[k][h*64+n]
        int id = b * 256 + t;
        int h = id >> 14, n = (id >> 8) & 63, k = id & 255;
        int dst = (h * 64 + n) * 256 + ((((k >> 3) ^ (n & 31)) & 31) << 3) + (k & 7);
        B0p[dst] = (_Float16)W0s[(size_t)k * 256 + h * 64 + n];
    } else if (b < 448) {          // B1p[h][n(48)][swz k]  <- W1s[k][h*47+n] (n<47)
        int id = (b - 256) * 256 + t;
        int np = id >> 8, k = id & 255;
        int h = np / 48, n = np % 48;
        int dst = np * 256 + ((((k >> 3) ^ (n & 31)) & 31) << 3) + (k & 7);
        B1p[dst] = (n < NCLS) ? (_Float16)W1s[(size_t)k * HD1 + h * NCLS + n] : (_Float16)0.f;
    } else if (b == 448) {         // vr0T[h*256+k]
        for (int i = t; i < 1024; i += 256) {
            int h = i >> 8, k = i & 255;
            float s = 0.f;
            for (int d = 0; d < 64; ++d)
                s += W0d[(size_t)k * 256 + h * 64 + d] * ar0[h * 64 + d];
            vr0T[h * 256 + k] = s;
        }
    } else if (b == 449) {         // vl0T[h*256+k]
        for (int i = t; i < 1024; i += 256) {
            int h = i >> 8, k = i & 255;
            float s = 0.f;
            for (int d = 0; d < 64; ++d)
                s += W0s[(size_t)k * 256 + h * 64 + d] * al0[h * 64 + d];
            vl0T[h * 256 + k] = s;
        }
    } else if (b == 450) {         // vl1T[h*256+k]
        for (int i = t; i < 1024; i += 256) {
            int h = i >> 8, k = i & 255;
            float s = 0.f;
            for (int d = 0; d < NCLS; ++d)
                s += W1s[(size_t)k * HD1 + h * NCLS + d] * al1[h * NCLS + d];
            vl1T[h * 256 + k] = s;
        }
    } else {                       // vr1T[h*256+k]
        for (int i = t; i < 1024; i += 256) {
            int h = i >> 8, k = i & 255;
            float s = 0.f;
            for (int d = 0; d < NCLS; ++d)
                s += W1d[(size_t)k * HD1 + h * NCLS + d] * ar1[h * NCLS + d];
            vr1T[h * 256 + k] = s;
        }
    }
}

// ---------------- streaming cvt + fused el/er GEMVs (measured ~5.5 TB/s) ------------
__global__ __launch_bounds__(256) void cvt_lr(const float* __restrict__ x,
        const float* __restrict__ vlT, const float* __restrict__ vrT,
        _Float16* __restrict__ xh, float* __restrict__ el, float* __restrict__ er,
        int M, int Mr) {
    int wv = threadIdx.x >> 6, lane = threadIdx.x & 63;
    int row = blockIdx.x * 4 + wv;
    if (row >= M) return;
    float4 xa = *(const float4*)(x + (size_t)row * IN + lane * 4);
    half4 hv;
    hv[0] = (_Float16)xa.x; hv[1] = (_Float16)xa.y;
    hv[2] = (_Float16)xa.z; hv[3] = (_Float16)xa.w;
    *(half4*)(xh + (size_t)row * IN + lane * 4) = hv;
    float sl[4], sr[4];
    bool do_r = row < Mr;
#pragma unroll
    for (int h = 0; h < 4; ++h) {
        float4 v = *(const float4*)(vlT + h * IN + lane * 4);
        sl[h] = xa.x * v.x + xa.y * v.y + xa.z * v.z + xa.w * v.w;
        float4 u = *(const float4*)(vrT + h * IN + lane * 4);
        sr[h] = xa.x * u.x + xa.y * u.y + xa.z * u.z + xa.w * u.w;
    }
#pragma unroll
    for (int off = 32; off; off >>= 1)
#pragma unroll
        for (int h = 0; h < 4; ++h) {
            sl[h] += __shfl_xor(sl[h], off);
            sr[h] += __shfl_xor(sr[h], off);
        }
    if (lane == 0) {
        *(float4*)(el + (size_t)row * 4) = make_float4(sl[0], sl[1], sl[2], sl[3]);
        if (do_r)
            *(float4*)(er + (size_t)row * 4) = make_float4(sr[0], sr[1], sr[2], sr[3]);
    }
}

// el (all rows) + er (rows < Mr) from f16 A, natural [*,256] layout
__global__ __launch_bounds__(256) void gemv_lr_f16(const _Float16* __restrict__ A,
        const float* __restrict__ vlT, const float* __restrict__ vrT,
        float* __restrict__ el, float* __restrict__ er, int M, int Mr) {
    int wv = threadIdx.x >> 6, lane = threadIdx.x & 63;
    int row = blockIdx.x * 4 + wv;
    if (row >= M) return;
    half4 ah = *(const half4*)(A + (size_t)row * IN + lane * 4);
    float a0 = (float)ah[0], a1 = (float)ah[1], a2 = (float)ah[2], a3 = (float)ah[3];
    float sl[4], sr[4];
#pragma unroll
    for (int h = 0; h < 4; ++h) {
        float4 v = *(const float4*)(vlT + h * IN + lane * 4);
        sl[h] = a0 * v.x + a1 * v.y + a2 * v.z + a3 * v.w;
        float4 u = *(const float4*)(vrT + h * IN + lane * 4);
        sr[h] = a0 * u.x + a1 * u.y + a2 * u.z + a3 * u.w;
    }
#pragma unroll
    for (int off = 32; off; off >>= 1)
#pragma unroll
        for (int h = 0; h < 4; ++h) {
            sl[h] += __shfl_xor(sl[h], off);
            sr[h] += __shfl_xor(sr[h], off);
        }
    if (lane == 0) {
        *(float4*)(el + (size_t)row * 4) = make_float4(sl[0], sl[1], sl[2], sl[3]);
        if (row < Mr)
            *(float4*)(er + (size_t)row * 4) = make_float4(sr[0], sr[1], sr[2], sr[3]);
    }
}

// ---------------- per-head x-space aggregation ----------------
// One wave per dst node: gather src rows (f16 [*,256]), per-head softmax weights,
// accumulate 4 head-planes of 256-wide f32, normalize, store f16 planes.
__global__ __launch_bounds__(256) void aggx(const int* __restrict__ ssrc,
        const int* __restrict__ offs, int obase,
        const float* __restrict__ el, const float* __restrict__ er,
        const _Float16* __restrict__ srcF, _Float16* __restrict__ aggP,
        size_t PS, int nd) {
    int wv = threadIdx.x >> 6, lane = threadIdx.x & 63;
    int d = blockIdx.x * 4 + wv;
    if (d >= nd) return;
    int beg = offs[obase + d], end = offs[obase + d + 1];
    float4 er4 = *(const float4*)(er + (size_t)d * 4);
    float erv[4] = {er4.x, er4.y, er4.z, er4.w};
    float acc[4][4];
#pragma unroll
    for (int h = 0; h < 4; ++h)
#pragma unroll
        for (int e = 0; e < 4; ++e) acc[h][e] = 0.f;
    float S[4] = {0.f, 0.f, 0.f, 0.f};
    for (int j0 = beg; j0 < end; j0 += 64) {
        int nn = min(64, end - j0);
        int myidx = (lane < nn) ? ssrc[j0 + lane] : 0;
        int j = 0;
        for (; j + 2 <= nn; j += 2) {
            int sa = __shfl(myidx, j), sb = __shfl(myidx, j + 1);
            float4 ea = *(const float4*)(el + (size_t)sa * 4);
            float4 eb = *(const float4*)(el + (size_t)sb * 4);
            half4 xa = *(const half4*)(srcF + (size_t)sa * 256 + lane * 4);
            half4 xb = *(const half4*)(srcF + (size_t)sb * 256 + lane * 4);
            float eav[4] = {ea.x, ea.y, ea.z, ea.w};
            float ebv[4] = {eb.x, eb.y, eb.z, eb.w};
            float wa[4], wb[4];
#pragma unroll
            for (int h = 0; h < 4; ++h) {
                wa[h] = __expf(leaky(eav[h] + erv[h]));
                wb[h] = __expf(leaky(ebv[h] + erv[h]));
                S[h] += wa[h] + wb[h];
            }
            float fa[4] = {(float)xa[0], (float)xa[1], (float)xa[2], (float)xa[3]};
            float fb[4] = {(float)xb[0], (float)xb[1], (float)xb[2], (float)xb[3]};
#pragma unroll
            for (int h = 0; h < 4; ++h)
#pragma unroll
                for (int e = 0; e < 4; ++e)
                    acc[h][e] += wa[h] * fa[e] + wb[h] * fb[e];
        }
        for (; j < nn; ++j) {
            int s = __shfl(myidx, j);
            float4 ea = *(const float4*)(el + (size_t)s * 4);
            half4 xa = *(const half4*)(srcF + (size_t)s * 256 + lane * 4);
            float eav[4] = {ea.x, ea.y, ea.z, ea.w};
            float wa[4];
#pragma unroll
            for (int h = 0; h < 4; ++h) {
                wa[h] = __expf(leaky(eav[h] + erv[h]));
                S[h] += wa[h];
            }
            float fa[4] = {(float)xa[0], (float)xa[1], (float)xa[2], (float)xa[3]};
#pragma unroll
            for (int h = 0; h < 4; ++h)
#pragma unroll
                for (int e = 0; e < 4; ++e)
                    acc[h][e] += wa[h] * fa[e];
        }
    }
#pragma unroll
    for (int h = 0; h < 4; ++h) {
        float inv = S[h] > 0.f ? 1.f / S[h] : 0.f;
        half4 o;
#pragma unroll
        for (int e = 0; e < 4; ++e) o[e] = (_Float16)(acc[h][e] * inv);
        *(half4*)(aggP + (size_t)h * PS + (size_t)d * 256 + lane * 4) = o;
    }
}

// ---------------- per-head wave-autonomous MFMA GEMM ----------------
// blockIdx.y = head plane. B-plane (NCOLS x 256, pre-swizzled) in LDS; each wave
// owns 16-row tiles, A double-buffered in registers, counted vmcnt, no in-loop
// barriers (r11-verified loop). Epilogue: +bias [, relu], writes col stripe.
template <int NCOLS, int CV, bool RELU, bool F32OUT>
__global__ __launch_bounds__(512, 2) void gemmp(const _Float16* __restrict__ Aplanes,
        size_t APS, const _Float16* __restrict__ Bplanes, const float* __restrict__ bias,
        void* __restrict__ Z, int zstride, int M, int ntiles) {
    constexpr int NCF = NCOLS / 16;
    __shared__ __align__(16) _Float16 Bs[NCOLS * 256];
    const int t = threadIdx.x, l = t & 63, w = t >> 6;
    const int lr = l & 15, lh = l >> 4;
    const int hplane = blockIdx.y;
    const _Float16* Ah  = Aplanes + (size_t)hplane * APS;
    const _Float16* BtS = Bplanes + (size_t)hplane * NCOLS * 256;

    constexpr int BI = NCOLS / 16;
#pragma unroll
    for (int it = 0; it < BI; ++it) {
        int c = it * 512 + t;
        gload16(BtS + c * 8, (char*)Bs + c * 16);
    }
    __syncthreads();   // only barrier

    const int NW = gridDim.x * 8;
    const int gw = blockIdx.x * 8 + w;

    half8 p0[8], p1[8];

    auto issue = [&](int tile, half8 (&p)[8]) {
        int row = tile * 16 + lr; if (row >= M) row = M - 1;
        const _Float16* ap = Ah + (size_t)row * 256 + lh * 8;
#pragma unroll
        for (int ks = 0; ks < 8; ++ks) p[ks] = *(const half8*)(ap + ks * 32);
        __builtin_amdgcn_sched_barrier(0);
    };

    auto compute = [&](int tile, half8 (&p)[8]) {
        f32x4 acc[NCF];
#pragma unroll
        for (int cf = 0; cf < NCF; ++cf) {
            acc[cf][0] = 0.f; acc[cf][1] = 0.f; acc[cf][2] = 0.f; acc[cf][3] = 0.f;
        }
#pragma unroll
        for (int ks = 0; ks < 8; ++ks) {
#pragma unroll
            for (int cf = 0; cf < NCF; ++cf) {
                int colr = cf * 16 + lr;
                half8 bf = *(const half8*)&Bs[colr * 256 +
                                              ((((ks * 4 + lh) ^ (colr & 31)) & 31) << 3)];
                acc[cf] = __builtin_amdgcn_mfma_f32_16x16x32_f16(p[ks], bf, acc[cf], 0, 0, 0);
            }
        }
#pragma unroll
        for (int cf = 0; cf < NCF; ++cf) {
            int col = cf * 16 + lr;
            if (col < CV) {
                float bcol = bias[hplane * CV + col];
#pragma unroll
                for (int r = 0; r < 4; ++r) {
                    int row = tile * 16 + lh * 4 + r;
                    if (row < M) {
                        float v = acc[cf][r] + bcol;
                        if constexpr (RELU) v = fmaxf(v, 0.f);
                        if constexpr (F32OUT)
                            ((float*)Z)[(size_t)row * zstride + hplane * CV + col] = v;
                        else
                            ((_Float16*)Z)[(size_t)row * zstride + hplane * CV + col] =
                                (_Float16)v;
                    }
                }
            }
        }
    };

    if (gw < ntiles) issue(gw, p0);
    for (int tt = gw; tt < ntiles; tt += 2 * NW) {
        int t1 = tt + NW;
        if (t1 < ntiles) {
            issue(t1, p1);
            asm volatile("s_waitcnt vmcnt(8)" ::: "memory");
        } else {
            asm volatile("s_waitcnt vmcnt(0)" ::: "memory");
        }
        compute(tt, p0);
        if (t1 < ntiles) {
            int t2 = tt + 2 * NW;
            if (t2 < ntiles) {
                issue(t2, p0);
                asm volatile("s_waitcnt vmcnt(8)" ::: "memory");
            } else {
                asm volatile("s_waitcnt vmcnt(0)" ::: "memory");
            }
            compute(t1, p1);
        }
    }
}

// combined histogram over both layers' edges (counts = [ND0 | ND1])
__global__ void hist2_k(const int* __restrict__ dst0, int E0,
                        const int* __restrict__ dst1, int E1, int* __restrict__ counts) {
    int i = blockIdx.x * blockDim.x + threadIdx.x;
    if (i < E0) atomicAdd(&counts[dst0[i]], 1);
    else if (i < E0 + E1) atomicAdd(&counts[ND0 + dst1[i - E0]], 1);
}

// ---- 3-kernel parallel exclusive scan ----
__global__ __launch_bounds__(256) void scan1_k(const int* __restrict__ counts, int n,
                                               int* __restrict__ part) {
    __shared__ int ws[4];
    int i = blockIdx.x * 256 + threadIdx.x;
    int lane = threadIdx.x & 63, wv = threadIdx.x >> 6;
    int s = (i < n) ? counts[i] : 0;
#pragma unroll
    for (int off = 32; off; off >>= 1) s += __shfl_xor(s, off);
    if (lane == 0) ws[wv] = s;
    __syncthreads();
    if (threadIdx.x == 0) part[blockIdx.x] = ws[0] + ws[1] + ws[2] + ws[3];
}

__global__ __launch_bounds__(256) void scan2_k(int* __restrict__ part, int nb) {
    __shared__ int ws[4];
    int tid = threadIdx.x, lane = tid & 63, wv = tid >> 6;
    int v = (tid < nb) ? part[tid] : 0;
    int x = v;
#pragma unroll
    for (int off = 1; off < 64; off <<= 1) {
        int u = __shfl_up(x, off);
        if (lane >= off) x += u;
    }
    if (lane == 63) ws[wv] = x;
    __syncthreads();
    int base = 0;
    for (int k = 0; k < wv; ++k) base += ws[k];
    if (tid < nb) part[tid] = base + x - v;
}

__global__ __launch_bounds__(256) void scan3_k(const int* __restrict__ counts, int n,
        const int* __restrict__ part, int* __restrict__ offsets, int* __restrict__ cursor) {
    __shared__ int ws[4];
    int i = blockIdx.x * 256 + threadIdx.x;
    int lane = threadIdx.x & 63, wv = threadIdx.x >> 6;
    int v = (i < n) ? counts[i] : 0;
    int x = v;
#pragma unroll
    for (int off = 1; off < 64; off <<= 1) {
        int u = __shfl_up(x, off);
        if (lane >= off) x += u;
    }
    if (lane == 63) ws[wv] = x;
    __syncthreads();
    int base = part[blockIdx.x];
    for (int k = 0; k < wv; ++k) base += ws[k];
    int off_ = base + x - v;
    if (i < n) { offsets[i] = off_; cursor[i] = off_; }
    if (i == n - 1) offsets[n] = off_ + v;
}

__global__ void scatter2_k(const int* __restrict__ src0, const int* __restrict__ dst0, int E0,
                           const int* __restrict__ src1, const int* __restrict__ dst1, int E1,
                           int* __restrict__ cursor, int* __restrict__ ssrc) {
    int i = blockIdx.x * blockDim.x + threadIdx.x;
    if (i < E0) {
        int p = atomicAdd(&cursor[dst0[i]], 1);
        ssrc[p] = src0[i];
    } else if (i < E0 + E1) {
        int j = i - E0;
        int p = atomicAdd(&cursor[ND0 + dst1[j]], 1);
        ssrc[p] = src1[j];
    }
}

// mean over heads + log_softmax; one wave per node (o1 f32 [*,188])
__global__ __launch_bounds__(256) void final_k(const float* __restrict__ o1,
        float* __restrict__ y, int n) {
    int wave = threadIdx.x >> 6, lane = threadIdx.x & 63;
    int node = blockIdx.x * 4 + wave;
    if (node >= n) return;
    const float* r = o1 + (size_t)node * HD1;
    float vv = 0.f, v = -INFINITY;
    if (lane < NCLS) {
        vv = 0.25f * (r[lane] + r[lane + NCLS] + r[lane + 2 * NCLS] + r[lane + 3 * NCLS]);
        v = vv;
    }
    float mx = v;
#pragma unroll
    for (int off = 32; off; off >>= 1) mx = fmaxf(mx, __shfl_xor(mx, off));
    float p = (lane < NCLS) ? __expf(vv - mx) : 0.f;
    float sum = p;
#pragma unroll
    for (int off = 32; off; off >>= 1) sum += __shfl_xor(sum, off);
    if (lane < NCLS) y[(size_t)node * NCLS + lane] = vv - mx - logf(sum);
}

extern "C" void kernel_launch(void* const* d_in, const int* in_sizes, int n_in,
                              void* d_out, int out_size, void* d_ws, size_t ws_size,
                              hipStream_t stream) {
    const float* x    = (const float*)d_in[0];
    const int*   src0 = (const int*)d_in[1];
    const int*   dst0 = (const int*)d_in[2];
    const int*   src1 = (const int*)d_in[3];
    const int*   dst1 = (const int*)d_in[4];
    const float* W0s  = (const float*)d_in[7];
    const float* W0d  = (const float*)d_in[8];
    const float* al0  = (const float*)d_in[9];
    const float* ar0  = (const float*)d_in[10];
    const float* b0   = (const float*)d_in[11];
    const float* W1s  = (const float*)d_in[12];
    const float* W1d  = (const float*)d_in[13];
    const float* al1  = (const float*)d_in[14];
    const float* ar1  = (const float*)d_in[15];
    const float* b1   = (const float*)d_in[16];
    const int E0 = in_sizes[1], E1 = in_sizes[3];
    const int NS0 = in_sizes[0] / IN;

    char* p = (char*)d_ws;
    auto take = [&](size_t bytes) {
        char* r = p;
        p += (bytes + 255) & ~(size_t)255;
        return r;
    };
    _Float16* xh    = (_Float16*)take((size_t)NS0 * 256 * 2);
    _Float16* aggP0 = (_Float16*)take((size_t)4 * ND0 * 256 * 2);
    _Float16* hbuf  = (_Float16*)take((size_t)ND0 * 256 * 2);
    _Float16* aggP1 = (_Float16*)take((size_t)4 * ND1 * 256 * 2);
    float*    o1    = (float*)take((size_t)ND1 * HD1 * 4);
    float*    el0   = (float*)take((size_t)NS0 * 4 * 4);
    float*    er0   = (float*)take((size_t)ND0 * 4 * 4);
    float*    el1   = (float*)take((size_t)ND0 * 4 * 4);
    float*    er1   = (float*)take((size_t)ND1 * 4 * 4);
    _Float16* B0p   = (_Float16*)take((size_t)4 * 64 * 256 * 2);
    _Float16* B1p   = (_Float16*)take((size_t)4 * 48 * 256 * 2);
    float*    vl0T  = (float*)take(4 * 256 * 4);
    float*    vr0T  = (float*)take(4 * 256 * 4);
    float*    vl1T  = (float*)take(4 * 256 * 4);
    float*    vr1T  = (float*)take(4 * 256 * 4);
    const int NDT = ND0 + ND1;
    int* counts = (int*)take((size_t)NDT * 4);
    int* offs   = (int*)take((size_t)(NDT + 1) * 4);
    int* cur    = (int*)take((size_t)NDT * 4);
    int* ss     = (int*)take((size_t)(E0 + E1) * 4);
    int* part   = (int*)take(256 * 4);

    const int NB = (NDT + 255) / 256;
    const int NT0 = (ND0 + 15) / 16, NT1 = (ND1 + 15) / 16;

    hipMemsetAsync(counts, 0, (size_t)NDT * 4, stream);

    prep_k<<<452, 256, 0, stream>>>(W0s, W1s, W0d, W1d, al0, ar0, al1, ar1,
                                    B0p, B1p, vl0T, vr0T, vl1T, vr1T);
    hist2_k<<<(E0 + E1 + 255) / 256, 256, 0, stream>>>(dst0, E0, dst1, E1, counts);
    scan1_k<<<NB, 256, 0, stream>>>(counts, NDT, part);
    scan2_k<<<1, 256, 0, stream>>>(part, NB);
    scan3_k<<<NB, 256, 0, stream>>>(counts, NDT, part, offs, cur);
    scatter2_k<<<(E0 + E1 + 255) / 256, 256, 0, stream>>>(src0, dst0, E0, src1, dst1, E1,
                                                          cur, ss);

    // ---- layer 0 ----
    cvt_lr<<<(NS0 + 3) / 4, 256, 0, stream>>>(x, vl0T, vr0T, xh, el0, er0, NS0, ND0);
    aggx<<<(ND0 + 3) / 4, 256, 0, stream>>>(ss, offs, 0, el0, er0, xh,
                                            aggP0, (size_t)ND0 * 256, ND0);
    gemmp<64, 64, true, false><<<dim3(128, 4), 512, 0, stream>>>(
        aggP0, (size_t)ND0 * 256, B0p, b0, (void*)hbuf, 256, ND0, NT0);

    // ---- layer 1 ----
    gemv_lr_f16<<<(ND0 + 3) / 4, 256, 0, stream>>>(hbuf, vl1T, vr1T, el1, er1, ND0, ND1);
    aggx<<<(ND1 + 3) / 4, 256, 0, stream>>>(ss, offs, ND0, el1, er1, hbuf,
                                            aggP1, (size_t)ND1 * 256, ND1);
    gemmp<48, 47, false, true><<<dim3(32, 4), 512, 0, stream>>>(
        aggP1, (size_t)ND1 * 256, B1p, b1, (void*)o1, HD1, ND1, NT1);

    final_k<<<(ND1 + 3) / 4, 256, 0, stream>>>(o1, (float*)d_out, ND1);
}

// Round 13
// 362.769 us; speedup vs baseline: 1.0265x; 1.0265x over previous
//
#include <hip/hip_runtime.h>
#include <math.h>

typedef _Float16 half8 __attribute__((ext_vector_type(8)));
typedef _Float16 half4 __attribute__((ext_vector_type(4)));
typedef float f32x4 __attribute__((ext_vector_type(4)));

constexpr int IN    = 256;
constexpr int NCLS  = 47;
constexpr int HD1   = 188;
constexpr float NEG_SLOPE = 0.2f;
constexpr int ND0 = 50000, ND1 = 10000;

static __device__ __forceinline__ float leaky(float x) {
    return x >= 0.f ? x : NEG_SLOPE * x;
}

__device__ __forceinline__ void gload16(const void* g, void* l) {
    __builtin_amdgcn_global_load_lds((const __attribute__((address_space(1))) void*)g,
                                     (__attribute__((address_space(3))) void*)l, 16, 0, 0);
}

// ---------------- prep: per-head pre-swizzled weight planes + folded attn vectors ----
// swz(k,n) = (((k>>3) ^ (n&31)) & 31)<<3 | (k&7)
__global__ __launch_bounds__(256) void prep_k(
        const float* __restrict__ W0s, const float* __restrict__ W1s,
        const float* __restrict__ W0d, const float* __restrict__ W1d,
        const float* __restrict__ al0, const float* __restrict__ ar0,
        const float* __restrict__ al1, const float* __restrict__ ar1,
        _Float16* __restrict__ B0p, _Float16* __restrict__ B1p,
        float* __restrict__ vl0T, float* __restrict__ vr0T,
        float* __restrict__ vl1T, float* __restrict__ vr1T) {
    int b = blockIdx.x, t = threadIdx.x;
    if (b < 256) {                 // B0p[h][n(64)][swz k]  <- W0s[k][h*64+n]
        int id = b * 256 + t;
        int h = id >> 14, n = (id >> 8) & 63, k = id & 255;
        int dst = (h * 64 + n) * 256 + ((((k >> 3) ^ (n & 31)) & 31) << 3) + (k & 7);
        B0p[dst] = (_Float16)W0s[(size_t)k * 256 + h * 64 + n];
    } else if (b < 448) {          // B1p[h][n(48)][swz k]  <- W1s[k][h*47+n] (n<47)
        int id = (b - 256) * 256 + t;
        int np = id >> 8, k = id & 255;
        int h = np / 48, n = np % 48;
        int dst = np * 256 + ((((k >> 3) ^ (n & 31)) & 31) << 3) + (k & 7);
        B1p[dst] = (n < NCLS) ? (_Float16)W1s[(size_t)k * HD1 + h * NCLS + n] : (_Float16)0.f;
    } else if (b == 448) {         // vr0T[h*256+k]
        for (int i = t; i < 1024; i += 256) {
            int h = i >> 8, k = i & 255;
            float s = 0.f;
            for (int d = 0; d < 64; ++d)
                s += W0d[(size_t)k * 256 + h * 64 + d] * ar0[h * 64 + d];
            vr0T[h * 256 + k] = s;
        }
    } else if (b == 449) {         // vl0T[h*256+k]
        for (int i = t; i < 1024; i += 256) {
            int h = i >> 8, k = i & 255;
            float s = 0.f;
            for (int d = 0; d < 64; ++d)
                s += W0s[(size_t)k * 256 + h * 64 + d] * al0[h * 64 + d];
            vl0T[h * 256 + k] = s;
        }
    } else if (b == 450) {         // vl1T[h*256+k]
        for (int i = t; i < 1024; i += 256) {
            int h = i >> 8, k = i & 255;
            float s = 0.f;
            for (int d = 0; d < NCLS; ++d)
                s += W1s[(size_t)k * HD1 + h * NCLS + d] * al1[h * NCLS + d];
            vl1T[h * 256 + k] = s;
        }
    } else {                       // vr1T[h*256+k]
        for (int i = t; i < 1024; i += 256) {
            int h = i >> 8, k = i & 255;
            float s = 0.f;
            for (int d = 0; d < NCLS; ++d)
                s += W1d[(size_t)k * HD1 + h * NCLS + d] * ar1[h * NCLS + d];
            vr1T[h * 256 + k] = s;
        }
    }
}

// ---------------- streaming cvt + fused el/er GEMVs (measured ~5.5 TB/s) ------------
__global__ __launch_bounds__(256) void cvt_lr(const float* __restrict__ x,
        const float* __restrict__ vlT, const float* __restrict__ vrT,
        _Float16* __restrict__ xh, float* __restrict__ el, float* __restrict__ er,
        int M, int Mr) {
    int wv = threadIdx.x >> 6, lane = threadIdx.x & 63;
    int row = blockIdx.x * 4 + wv;
    if (row >= M) return;
    float4 xa = *(const float4*)(x + (size_t)row * IN + lane * 4);
    half4 hv;
    hv[0] = (_Float16)xa.x; hv[1] = (_Float16)xa.y;
    hv[2] = (_Float16)xa.z; hv[3] = (_Float16)xa.w;
    *(half4*)(xh + (size_t)row * IN + lane * 4) = hv;
    float sl[4], sr[4];
    bool do_r = row < Mr;
#pragma unroll
    for (int h = 0; h < 4; ++h) {
        float4 v = *(const float4*)(vlT + h * IN + lane * 4);
        sl[h] = xa.x * v.x + xa.y * v.y + xa.z * v.z + xa.w * v.w;
        float4 u = *(const float4*)(vrT + h * IN + lane * 4);
        sr[h] = xa.x * u.x + xa.y * u.y + xa.z * u.z + xa.w * u.w;
    }
#pragma unroll
    for (int off = 32; off; off >>= 1)
#pragma unroll
        for (int h = 0; h < 4; ++h) {
            sl[h] += __shfl_xor(sl[h], off);
            sr[h] += __shfl_xor(sr[h], off);
        }
    if (lane == 0) {
        *(float4*)(el + (size_t)row * 4) = make_float4(sl[0], sl[1], sl[2], sl[3]);
        if (do_r)
            *(float4*)(er + (size_t)row * 4) = make_float4(sr[0], sr[1], sr[2], sr[3]);
    }
}

// el (all rows) + er (rows < Mr) from f16 A, natural [*,256] layout
__global__ __launch_bounds__(256) void gemv_lr_f16(const _Float16* __restrict__ A,
        const float* __restrict__ vlT, const float* __restrict__ vrT,
        float* __restrict__ el, float* __restrict__ er, int M, int Mr) {
    int wv = threadIdx.x >> 6, lane = threadIdx.x & 63;
    int row = blockIdx.x * 4 + wv;
    if (row >= M) return;
    half4 ah = *(const half4*)(A + (size_t)row * IN + lane * 4);
    float a0 = (float)ah[0], a1 = (float)ah[1], a2 = (float)ah[2], a3 = (float)ah[3];
    float sl[4], sr[4];
#pragma unroll
    for (int h = 0; h < 4; ++h) {
        float4 v = *(const float4*)(vlT + h * IN + lane * 4);
        sl[h] = a0 * v.x + a1 * v.y + a2 * v.z + a3 * v.w;
        float4 u = *(const float4*)(vrT + h * IN + lane * 4);
        sr[h] = a0 * u.x + a1 * u.y + a2 * u.z + a3 * u.w;
    }
#pragma unroll
    for (int off = 32; off; off >>= 1)
#pragma unroll
        for (int h = 0; h < 4; ++h) {
            sl[h] += __shfl_xor(sl[h], off);
            sr[h] += __shfl_xor(sr[h], off);
        }
    if (lane == 0) {
        *(float4*)(el + (size_t)row * 4) = make_float4(sl[0], sl[1], sl[2], sl[3]);
        if (row < Mr)
            *(float4*)(er + (size_t)row * 4) = make_float4(sr[0], sr[1], sr[2], sr[3]);
    }
}

// ---------------- per-head x-space aggregation (x4 unrolled) ----------------
__global__ __launch_bounds__(256) void aggx(const int* __restrict__ ssrc,
        const int* __restrict__ offs, int obase,
        const float* __restrict__ el, const float* __restrict__ er,
        const _Float16* __restrict__ srcF, _Float16* __restrict__ aggP,
        size_t PS, int nd) {
    int wv = threadIdx.x >> 6, lane = threadIdx.x & 63;
    int d = blockIdx.x * 4 + wv;
    if (d >= nd) return;
    int beg = offs[obase + d], end = offs[obase + d + 1];
    float4 er4 = *(const float4*)(er + (size_t)d * 4);
    float erv[4] = {er4.x, er4.y, er4.z, er4.w};
    float acc[4][4];
#pragma unroll
    for (int h = 0; h < 4; ++h)
#pragma unroll
        for (int e = 0; e < 4; ++e) acc[h][e] = 0.f;
    float S[4] = {0.f, 0.f, 0.f, 0.f};
    for (int j0 = beg; j0 < end; j0 += 64) {
        int nn = min(64, end - j0);
        int myidx = (lane < nn) ? ssrc[j0 + lane] : 0;
        int j = 0;
        for (; j + 4 <= nn; j += 4) {
            int s0 = __shfl(myidx, j),     s1 = __shfl(myidx, j + 1);
            int s2 = __shfl(myidx, j + 2), s3 = __shfl(myidx, j + 3);
            float4 e0 = *(const float4*)(el + (size_t)s0 * 4);
            float4 e1 = *(const float4*)(el + (size_t)s1 * 4);
            float4 e2 = *(const float4*)(el + (size_t)s2 * 4);
            float4 e3 = *(const float4*)(el + (size_t)s3 * 4);
            half4 x0 = *(const half4*)(srcF + (size_t)s0 * 256 + lane * 4);
            half4 x1 = *(const half4*)(srcF + (size_t)s1 * 256 + lane * 4);
            half4 x2 = *(const half4*)(srcF + (size_t)s2 * 256 + lane * 4);
            half4 x3 = *(const half4*)(srcF + (size_t)s3 * 256 + lane * 4);
            float ev0[4] = {e0.x, e0.y, e0.z, e0.w};
            float ev1[4] = {e1.x, e1.y, e1.z, e1.w};
            float ev2[4] = {e2.x, e2.y, e2.z, e2.w};
            float ev3[4] = {e3.x, e3.y, e3.z, e3.w};
            float w0[4], w1[4], w2[4], w3[4];
#pragma unroll
            for (int h = 0; h < 4; ++h) {
                w0[h] = __expf(leaky(ev0[h] + erv[h]));
                w1[h] = __expf(leaky(ev1[h] + erv[h]));
                w2[h] = __expf(leaky(ev2[h] + erv[h]));
                w3[h] = __expf(leaky(ev3[h] + erv[h]));
                S[h] += (w0[h] + w1[h]) + (w2[h] + w3[h]);
            }
            float f0[4] = {(float)x0[0], (float)x0[1], (float)x0[2], (float)x0[3]};
            float f1[4] = {(float)x1[0], (float)x1[1], (float)x1[2], (float)x1[3]};
            float f2[4] = {(float)x2[0], (float)x2[1], (float)x2[2], (float)x2[3]};
            float f3[4] = {(float)x3[0], (float)x3[1], (float)x3[2], (float)x3[3]};
#pragma unroll
            for (int h = 0; h < 4; ++h)
#pragma unroll
                for (int e = 0; e < 4; ++e)
                    acc[h][e] += (w0[h] * f0[e] + w1[h] * f1[e])
                               + (w2[h] * f2[e] + w3[h] * f3[e]);
        }
        for (; j < nn; ++j) {
            int s = __shfl(myidx, j);
            float4 ea = *(const float4*)(el + (size_t)s * 4);
            half4 xa = *(const half4*)(srcF + (size_t)s * 256 + lane * 4);
            float eav[4] = {ea.x, ea.y, ea.z, ea.w};
            float wa[4];
#pragma unroll
            for (int h = 0; h < 4; ++h) {
                wa[h] = __expf(leaky(eav[h] + erv[h]));
                S[h] += wa[h];
            }
            float fa[4] = {(float)xa[0], (float)xa[1], (float)xa[2], (float)xa[3]};
#pragma unroll
            for (int h = 0; h < 4; ++h)
#pragma unroll
                for (int e = 0; e < 4; ++e)
                    acc[h][e] += wa[h] * fa[e];
        }
    }
#pragma unroll
    for (int h = 0; h < 4; ++h) {
        float inv = S[h] > 0.f ? 1.f / S[h] : 0.f;
        half4 o;
#pragma unroll
        for (int e = 0; e < 4; ++e) o[e] = (_Float16)(acc[h][e] * inv);
        *(half4*)(aggP + (size_t)h * PS + (size_t)d * 256 + lane * 4) = o;
    }
}

// ---------------- per-head wave-autonomous MFMA GEMM ----------------
// TRN=true: bias/relu in fragment space, 16x64 tile transposed through wave-private
// LDS, stores are 2x half8 coalesced instructions (1 KB each) -> fast retirement
// in the single vmcnt queue (CDNA has no separate store counter).
template <int NCOLS, int CV, bool RELU, bool F32OUT, bool TRN>
__global__ __launch_bounds__(512, 2) void gemmp(const _Float16* __restrict__ Aplanes,
        size_t APS, const _Float16* __restrict__ Bplanes, const float* __restrict__ bias,
        void* __restrict__ Z, int zstride, int M, int ntiles) {
    constexpr int NCF = NCOLS / 16;
    __shared__ __align__(16) _Float16 Bs[NCOLS * 256];
    __shared__ __align__(16) _Float16 Ts[TRN ? 8 * 16 * 72 : 8];
    const int t = threadIdx.x, l = t & 63, w = t >> 6;
    const int lr = l & 15, lh = l >> 4;
    const int hplane = blockIdx.y;
    const _Float16* Ah  = Aplanes + (size_t)hplane * APS;
    const _Float16* BtS = Bplanes + (size_t)hplane * NCOLS * 256;
    _Float16* Tw = &Ts[TRN ? w * 16 * 72 : 0];

    constexpr int BI = NCOLS / 16;
#pragma unroll
    for (int it = 0; it < BI; ++it) {
        int c = it * 512 + t;
        gload16(BtS + c * 8, (char*)Bs + c * 16);
    }
    __syncthreads();   // only barrier

    float bcol[NCF];
#pragma unroll
    for (int cf = 0; cf < NCF; ++cf) {
        int col = cf * 16 + lr;
        bcol[cf] = (col < CV) ? bias[hplane * CV + col] : 0.f;
    }

    const int NW = gridDim.x * 8;
    const int gw = blockIdx.x * 8 + w;

    half8 p0[8], p1[8];

    auto issue = [&](int tile, half8 (&p)[8]) {
        int row = tile * 16 + lr; if (row >= M) row = M - 1;
        const _Float16* ap = Ah + (size_t)row * 256 + lh * 8;
#pragma unroll
        for (int ks = 0; ks < 8; ++ks) p[ks] = *(const half8*)(ap + ks * 32);
        __builtin_amdgcn_sched_barrier(0);
    };

    auto compute = [&](int tile, half8 (&p)[8]) {
        f32x4 acc[NCF];
#pragma unroll
        for (int cf = 0; cf < NCF; ++cf) {
            acc[cf][0] = 0.f; acc[cf][1] = 0.f; acc[cf][2] = 0.f; acc[cf][3] = 0.f;
        }
#pragma unroll
        for (int ks = 0; ks < 8; ++ks) {
#pragma unroll
            for (int cf = 0; cf < NCF; ++cf) {
                int colr = cf * 16 + lr;
                half8 bf = *(const half8*)&Bs[colr * 256 +
                                              ((((ks * 4 + lh) ^ (colr & 31)) & 31) << 3)];
                acc[cf] = __builtin_amdgcn_mfma_f32_16x16x32_f16(p[ks], bf, acc[cf], 0, 0, 0);
            }
        }
        if constexpr (TRN) {
            // bias+relu in fragment space, transpose via wave-private LDS
#pragma unroll
            for (int cf = 0; cf < NCF; ++cf) {
#pragma unroll
                for (int r = 0; r < 4; ++r) {
                    float v = acc[cf][r] + bcol[cf];
                    if constexpr (RELU) v = fmaxf(v, 0.f);
                    Tw[(lh * 4 + r) * 72 + cf * 16 + lr] = (_Float16)v;
                }
            }
            // wave-coherent: compiler inserts lgkmcnt before dependent reads
#pragma unroll
            for (int i = 0; i < 2; ++i) {
                int trow = i * 8 + (l >> 3);
                half8 hv = *(const half8*)&Tw[trow * 72 + (l & 7) * 8];
                int node = tile * 16 + trow;
                if (node < M)
                    *(half8*)((_Float16*)Z + (size_t)node * zstride + hplane * NCOLS
                              + (l & 7) * 8) = hv;
            }
        } else {
#pragma unroll
            for (int cf = 0; cf < NCF; ++cf) {
                int col = cf * 16 + lr;
                if (col < CV) {
#pragma unroll
                    for (int r = 0; r < 4; ++r) {
                        int row = tile * 16 + lh * 4 + r;
                        if (row < M) {
                            float v = acc[cf][r] + bcol[cf];
                            if constexpr (RELU) v = fmaxf(v, 0.f);
                            if constexpr (F32OUT)
                                ((float*)Z)[(size_t)row * zstride + hplane * CV + col] = v;
                            else
                                ((_Float16*)Z)[(size_t)row * zstride + hplane * CV + col] =
                                    (_Float16)v;
                        }
                    }
                }
            }
        }
    };

    if (gw < ntiles) issue(gw, p0);
    for (int tt = gw; tt < ntiles; tt += 2 * NW) {
        int t1 = tt + NW;
        if (t1 < ntiles) {
            issue(t1, p1);
            asm volatile("s_waitcnt vmcnt(8)" ::: "memory");
        } else {
            asm volatile("s_waitcnt vmcnt(0)" ::: "memory");
        }
        compute(tt, p0);
        if (t1 < ntiles) {
            int t2 = tt + 2 * NW;
            if (t2 < ntiles) {
                issue(t2, p0);
                asm volatile("s_waitcnt vmcnt(8)" ::: "memory");
            } else {
                asm volatile("s_waitcnt vmcnt(0)" ::: "memory");
            }
            compute(t1, p1);
        }
    }
}

// combined histogram over both layers' edges (counts = [ND0 | ND1])
__global__ void hist2_k(const int* __restrict__ dst0, int E0,
                        const int* __restrict__ dst1, int E1, int* __restrict__ counts) {
    int i = blockIdx.x * blockDim.x + threadIdx.x;
    if (i < E0) atomicAdd(&counts[dst0[i]], 1);
    else if (i < E0 + E1) atomicAdd(&counts[ND0 + dst1[i - E0]], 1);
}

// ---- 3-kernel parallel exclusive scan ----
__global__ __launch_bounds__(256) void scan1_k(const int* __restrict__ counts, int n,
                                               int* __restrict__ part) {
    __shared__ int ws[4];
    int i = blockIdx.x * 256 + threadIdx.x;
    int lane = threadIdx.x & 63, wv = threadIdx.x >> 6;
    int s = (i < n) ? counts[i] : 0;
#pragma unroll
    for (int off = 32; off; off >>= 1) s += __shfl_xor(s, off);
    if (lane == 0) ws[wv] = s;
    __syncthreads();
    if (threadIdx.x == 0) part[blockIdx.x] = ws[0] + ws[1] + ws[2] + ws[3];
}

__global__ __launch_bounds__(256) void scan2_k(int* __restrict__ part, int nb) {
    __shared__ int ws[4];
    int tid = threadIdx.x, lane = tid & 63, wv = tid >> 6;
    int v = (tid < nb) ? part[tid] : 0;
    int x = v;
#pragma unroll
    for (int off = 1; off < 64; off <<= 1) {
        int u = __shfl_up(x, off);
        if (lane >= off) x += u;
    }
    if (lane == 63) ws[wv] = x;
    __syncthreads();
    int base = 0;
    for (int k = 0; k < wv; ++k) base += ws[k];
    if (tid < nb) part[tid] = base + x - v;
}

__global__ __launch_bounds__(256) void scan3_k(const int* __restrict__ counts, int n,
        const int* __restrict__ part, int* __restrict__ offsets, int* __restrict__ cursor) {
    __shared__ int ws[4];
    int i = blockIdx.x * 256 + threadIdx.x;
    int lane = threadIdx.x & 63, wv = threadIdx.x >> 6;
    int v = (i < n) ? counts[i] : 0;
    int x = v;
#pragma unroll
    for (int off = 1; off < 64; off <<= 1) {
        int u = __shfl_up(x, off);
        if (lane >= off) x += u;
    }
    if (lane == 63) ws[wv] = x;
    __syncthreads();
    int base = part[blockIdx.x];
    for (int k = 0; k < wv; ++k) base += ws[k];
    int off_ = base + x - v;
    if (i < n) { offsets[i] = off_; cursor[i] = off_; }
    if (i == n - 1) offsets[n] = off_ + v;
}

__global__ void scatter2_k(const int* __restrict__ src0, const int* __restrict__ dst0, int E0,
                           const int* __restrict__ src1, const int* __restrict__ dst1, int E1,
                           int* __restrict__ cursor, int* __restrict__ ssrc) {
    int i = blockIdx.x * blockDim.x + threadIdx.x;
    if (i < E0) {
        int p = atomicAdd(&cursor[dst0[i]], 1);
        ssrc[p] = src0[i];
    } else if (i < E0 + E1) {
        int j = i - E0;
        int p = atomicAdd(&cursor[ND0 + dst1[j]], 1);
        ssrc[p] = src1[j];
    }
}

// mean over heads + log_softmax; one wave per node (o1 f32 [*,188])
__global__ __launch_bounds__(256) void final_k(const float* __restrict__ o1,
        float* __restrict__ y, int n) {
    int wave = threadIdx.x >> 6, lane = threadIdx.x & 63;
    int node = blockIdx.x * 4 + wave;
    if (node >= n) return;
    const float* r = o1 + (size_t)node * HD1;
    float vv = 0.f, v = -INFINITY;
    if (lane < NCLS) {
        vv = 0.25f * (r[lane] + r[lane + NCLS] + r[lane + 2 * NCLS] + r[lane + 3 * NCLS]);
        v = vv;
    }
    float mx = v;
#pragma unroll
    for (int off = 32; off; off >>= 1) mx = fmaxf(mx, __shfl_xor(mx, off));
    float p = (lane < NCLS) ? __expf(vv - mx) : 0.f;
    float sum = p;
#pragma unroll
    for (int off = 32; off; off >>= 1) sum += __shfl_xor(sum, off);
    if (lane < NCLS) y[(size_t)node * NCLS + lane] = vv - mx - logf(sum);
}

extern "C" void kernel_launch(void* const* d_in, const int* in_sizes, int n_in,
                              void* d_out, int out_size, void* d_ws, size_t ws_size,
                              hipStream_t stream) {
    const float* x    = (const float*)d_in[0];
    const int*   src0 = (const int*)d_in[1];
    const int*   dst0 = (const int*)d_in[2];
    const int*   src1 = (const int*)d_in[3];
    const int*   dst1 = (const int*)d_in[4];
    const float* W0s  = (const float*)d_in[7];
    const float* W0d  = (const float*)d_in[8];
    const float* al0  = (const float*)d_in[9];
    const float* ar0  = (const float*)d_in[10];
    const float* b0   = (const float*)d_in[11];
    const float* W1s  = (const float*)d_in[12];
    const float* W1d  = (const float*)d_in[13];
    const float* al1  = (const float*)d_in[14];
    const float* ar1  = (const float*)d_in[15];
    const float* b1   = (const float*)d_in[16];
    const int E0 = in_sizes[1], E1 = in_sizes[3];
    const int NS0 = in_sizes[0] / IN;

    char* p = (char*)d_ws;
    auto take = [&](size_t bytes) {
        char* r = p;
        p += (bytes + 255) & ~(size_t)255;
        return r;
    };
    _Float16* xh    = (_Float16*)take((size_t)NS0 * 256 * 2);
    _Float16* aggP0 = (_Float16*)take((size_t)4 * ND0 * 256 * 2);
    _Float16* hbuf  = (_Float16*)take((size_t)ND0 * 256 * 2);
    _Float16* aggP1 = (_Float16*)take((size_t)4 * ND1 * 256 * 2);
    float*    o1    = (float*)take((size_t)ND1 * HD1 * 4);
    float*    el0   = (float*)take((size_t)NS0 * 4 * 4);
    float*    er0   = (float*)take((size_t)ND0 * 4 * 4);
    float*    el1   = (float*)take((size_t)ND0 * 4 * 4);
    float*    er1   = (float*)take((size_t)ND1 * 4 * 4);
    _Float16* B0p   = (_Float16*)take((size_t)4 * 64 * 256 * 2);
    _Float16* B1p   = (_Float16*)take((size_t)4 * 48 * 256 * 2);
    float*    vl0T  = (float*)take(4 * 256 * 4);
    float*    vr0T  = (float*)take(4 * 256 * 4);
    float*    vl1T  = (float*)take(4 * 256 * 4);
    float*    vr1T  = (float*)take(4 * 256 * 4);
    const int NDT = ND0 + ND1;
    int* counts = (int*)take((size_t)NDT * 4);
    int* offs   = (int*)take((size_t)(NDT + 1) * 4);
    int* cur    = (int*)take((size_t)NDT * 4);
    int* ss     = (int*)take((size_t)(E0 + E1) * 4);
    int* part   = (int*)take(256 * 4);

    const int NB = (NDT + 255) / 256;
    const int NT0 = (ND0 + 15) / 16, NT1 = (ND1 + 15) / 16;

    hipMemsetAsync(counts, 0, (size_t)NDT * 4, stream);

    prep_k<<<452, 256, 0, stream>>>(W0s, W1s, W0d, W1d, al0, ar0, al1, ar1,
                                    B0p, B1p, vl0T, vr0T, vl1T, vr1T);
    hist2_k<<<(E0 + E1 + 255) / 256, 256, 0, stream>>>(dst0, E0, dst1, E1, counts);
    scan1_k<<<NB, 256, 0, stream>>>(counts, NDT, part);
    scan2_k<<<1, 256, 0, stream>>>(part, NB);
    scan3_k<<<NB, 256, 0, stream>>>(counts, NDT, part, offs, cur);
    scatter2_k<<<(E0 + E1 + 255) / 256, 256, 0, stream>>>(src0, dst0, E0, src1, dst1, E1,
                                                          cur, ss);

    // ---- layer 0 ----
    cvt_lr<<<(NS0 + 3) / 4, 256, 0, stream>>>(x, vl0T, vr0T, xh, el0, er0, NS0, ND0);
    aggx<<<(ND0 + 3) / 4, 256, 0, stream>>>(ss, offs, 0, el0, er0, xh,
                                            aggP0, (size_t)ND0 * 256, ND0);
    gemmp<64, 64, true, false, true><<<dim3(128, 4), 512, 0, stream>>>(
        aggP0, (size_t)ND0 * 256, B0p, b0, (void*)hbuf, 256, ND0, NT0);

    // ---- layer 1 ----
    gemv_lr_f16<<<(ND0 + 3) / 4, 256, 0, stream>>>(hbuf, vl1T, vr1T, el1, er1, ND0, ND1);
    aggx<<<(ND1 + 3) / 4, 256, 0, stream>>>(ss, offs, ND0, el1, er1, hbuf,
                                            aggP1, (size_t)ND1 * 256, ND1);
    gemmp<48, 47, false, true, false><<<dim3(32, 4), 512, 0, stream>>>(
        aggP1, (size_t)ND1 * 256, B1p, b1, (void*)o1, HD1, ND1, NT1);

    final_k<<<(ND1 + 3) / 4, 256, 0, stream>>>(o1, (float*)d_out, ND1);
}

// Round 14
// 310.371 us; speedup vs baseline: 1.1998x; 1.1688x over previous
//
#include <hip/hip_runtime.h>
#include <math.h>

typedef _Float16 half8 __attribute__((ext_vector_type(8)));
typedef _Float16 half4 __attribute__((ext_vector_type(4)));
typedef float f32x4 __attribute__((ext_vector_type(4)));

constexpr int IN    = 256;
constexpr int NCLS  = 47;
constexpr int HD1   = 188;
constexpr float NEG_SLOPE = 0.2f;
constexpr int ND0 = 50000, ND1 = 10000;

static __device__ __forceinline__ float leaky(float x) {
    return x >= 0.f ? x : NEG_SLOPE * x;
}

__device__ __forceinline__ void gload16(const void* g, void* l) {
    __builtin_amdgcn_global_load_lds((const __attribute__((address_space(1))) void*)g,
                                     (__attribute__((address_space(3))) void*)l, 16, 0, 0);
}

// Reduce 8 per-lane values across 64 lanes with 10 shuffles (vs 48 naive).
// Returns the total of value idx V = 4*b0 + 2*b1 + b2 (b = lane bits 0..2).
__device__ __forceinline__ float red8(const float v[8], int lane) {
    const int b0 = lane & 1, b1 = (lane >> 1) & 1, b2 = (lane >> 2) & 1;
    float K[4];
#pragma unroll
    for (int i = 0; i < 4; ++i) {
        float send = b0 ? v[i] : v[i + 4];
        float r = __shfl_xor(send, 1);
        K[i] = (b0 ? v[i + 4] : v[i]) + r;
    }
    float L[2];
#pragma unroll
    for (int i = 0; i < 2; ++i) {
        float send = b1 ? K[i] : K[i + 2];
        float r = __shfl_xor(send, 2);
        L[i] = (b1 ? K[i + 2] : K[i]) + r;
    }
    float send = b2 ? L[0] : L[1];
    float r = __shfl_xor(send, 4);
    float Mv = (b2 ? L[1] : L[0]) + r;
    Mv += __shfl_xor(Mv, 8);
    Mv += __shfl_xor(Mv, 16);
    Mv += __shfl_xor(Mv, 32);
    return Mv;
}

// ---------------- prep: per-head pre-swizzled weight planes + folded attn vectors ----
__global__ __launch_bounds__(256) void prep_k(
        const float* __restrict__ W0s, const float* __restrict__ W1s,
        const float* __restrict__ W0d, const float* __restrict__ W1d,
        const float* __restrict__ al0, const float* __restrict__ ar0,
        const float* __restrict__ al1, const float* __restrict__ ar1,
        _Float16* __restrict__ B0p, _Float16* __restrict__ B1p,
        float* __restrict__ vl0T, float* __restrict__ vr0T,
        float* __restrict__ vl1T, float* __restrict__ vr1T) {
    int b = blockIdx.x, t = threadIdx.x;
    if (b < 256) {                 // B0p[h][n(64)][swz k]
        int id = b * 256 + t;
        int h = id >> 14, n = (id >> 8) & 63, k = id & 255;
        int dst = (h * 64 + n) * 256 + ((((k >> 3) ^ (n & 31)) & 31) << 3) + (k & 7);
        B0p[dst] = (_Float16)W0s[(size_t)k * 256 + h * 64 + n];
    } else if (b < 448) {          // B1p[h][n(48)][swz k]
        int id = (b - 256) * 256 + t;
        int np = id >> 8, k = id & 255;
        int h = np / 48, n = np % 48;
        int dst = np * 256 + ((((k >> 3) ^ (n & 31)) & 31) << 3) + (k & 7);
        B1p[dst] = (n < NCLS) ? (_Float16)W1s[(size_t)k * HD1 + h * NCLS + n] : (_Float16)0.f;
    } else if (b == 448) {         // vr0T[h*256+k]
        for (int i = t; i < 1024; i += 256) {
            int h = i >> 8, k = i & 255;
            float s = 0.f;
            for (int d = 0; d < 64; ++d)
                s += W0d[(size_t)k * 256 + h * 64 + d] * ar0[h * 64 + d];
            vr0T[h * 256 + k] = s;
        }
    } else if (b == 449) {         // vl0T[h*256+k]
        for (int i = t; i < 1024; i += 256) {
            int h = i >> 8, k = i & 255;
            float s = 0.f;
            for (int d = 0; d < 64; ++d)
                s += W0s[(size_t)k * 256 + h * 64 + d] * al0[h * 64 + d];
            vl0T[h * 256 + k] = s;
        }
    } else if (b == 450) {         // vl1T[h*256+k]
        for (int i = t; i < 1024; i += 256) {
            int h = i >> 8, k = i & 255;
            float s = 0.f;
            for (int d = 0; d < NCLS; ++d)
                s += W1s[(size_t)k * HD1 + h * NCLS + d] * al1[h * NCLS + d];
            vl1T[h * 256 + k] = s;
        }
    } else {                       // vr1T[h*256+k]
        for (int i = t; i < 1024; i += 256) {
            int h = i >> 8, k = i & 255;
            float s = 0.f;
            for (int d = 0; d < NCLS; ++d)
                s += W1d[(size_t)k * HD1 + h * NCLS + d] * ar1[h * NCLS + d];
            vr1T[h * 256 + k] = s;
        }
    }
}

// ---------------- unified el/er GEMV (+optional f32->f16 cvt) ----------------
// Grid-stride wave-per-row; vl/vr hoisted to registers ONCE per wave; 10-shuffle
// multi-value reduce; two rows interleaved for ILP.
template <bool F32IN, bool WRITE_XH>
__global__ __launch_bounds__(256) void lr_k(const void* __restrict__ Xv,
        const float* __restrict__ vlT, const float* __restrict__ vrT,
        _Float16* __restrict__ xh, float* __restrict__ el, float* __restrict__ er,
        int M, int Mr) {
    const int wv = threadIdx.x >> 6, lane = threadIdx.x & 63;
    const int gw0 = blockIdx.x * 4 + wv, NW = gridDim.x * 4;
    float vl[4][4], vr[4][4];
#pragma unroll
    for (int h = 0; h < 4; ++h) {
        float4 v = *(const float4*)(vlT + h * 256 + lane * 4);
        vl[h][0] = v.x; vl[h][1] = v.y; vl[h][2] = v.z; vl[h][3] = v.w;
        float4 u = *(const float4*)(vrT + h * 256 + lane * 4);
        vr[h][0] = u.x; vr[h][1] = u.y; vr[h][2] = u.z; vr[h][3] = u.w;
    }
    const int l7 = lane & 7;
    const int jj = ((l7 >> 1) & 1) * 2 + ((l7 >> 2) & 1);
    const bool isL = (l7 & 1) == 0;

    auto dorow = [&](int row) {
        float xa[4];
        if constexpr (F32IN) {
            float4 tv = *(const float4*)((const float*)Xv + (size_t)row * 256 + lane * 4);
            xa[0] = tv.x; xa[1] = tv.y; xa[2] = tv.z; xa[3] = tv.w;
            if constexpr (WRITE_XH) {
                half4 hv;
                hv[0] = (_Float16)tv.x; hv[1] = (_Float16)tv.y;
                hv[2] = (_Float16)tv.z; hv[3] = (_Float16)tv.w;
                *(half4*)(xh + (size_t)row * 256 + lane * 4) = hv;
            }
        } else {
            half4 tv = *(const half4*)((const _Float16*)Xv + (size_t)row * 256 + lane * 4);
            xa[0] = (float)tv[0]; xa[1] = (float)tv[1];
            xa[2] = (float)tv[2]; xa[3] = (float)tv[3];
        }
        float v8[8];
#pragma unroll
        for (int h = 0; h < 4; ++h) {
            v8[h]     = xa[0] * vl[h][0] + xa[1] * vl[h][1]
                      + xa[2] * vl[h][2] + xa[3] * vl[h][3];
            v8[h + 4] = xa[0] * vr[h][0] + xa[1] * vr[h][1]
                      + xa[2] * vr[h][2] + xa[3] * vr[h][3];
        }
        float Mv = red8(v8, lane);
        if (lane < 8) {
            if (isL) el[(size_t)row * 4 + jj] = Mv;
            else if (row < Mr) er[(size_t)row * 4 + jj] = Mv;
        }
    };

    int row = gw0;
    for (; row + NW < M; row += 2 * NW) { dorow(row); dorow(row + NW); }
    if (row < M) dorow(row);
}

// ---------------- per-head x-space aggregation (x4 unrolled) ----------------
__global__ __launch_bounds__(256) void aggx(const int* __restrict__ ssrc,
        const int* __restrict__ offs, int obase,
        const float* __restrict__ el, const float* __restrict__ er,
        const _Float16* __restrict__ srcF, _Float16* __restrict__ aggP,
        size_t PS, int nd) {
    int wv = threadIdx.x >> 6, lane = threadIdx.x & 63;
    int d = blockIdx.x * 4 + wv;
    if (d >= nd) return;
    int beg = offs[obase + d], end = offs[obase + d + 1];
    float4 er4 = *(const float4*)(er + (size_t)d * 4);
    float erv[4] = {er4.x, er4.y, er4.z, er4.w};
    float acc[4][4];
#pragma unroll
    for (int h = 0; h < 4; ++h)
#pragma unroll
        for (int e = 0; e < 4; ++e) acc[h][e] = 0.f;
    float S[4] = {0.f, 0.f, 0.f, 0.f};
    for (int j0 = beg; j0 < end; j0 += 64) {
        int nn = min(64, end - j0);
        int myidx = (lane < nn) ? ssrc[j0 + lane] : 0;
        int j = 0;
        for (; j + 4 <= nn; j += 4) {
            int s0 = __shfl(myidx, j),     s1 = __shfl(myidx, j + 1);
            int s2 = __shfl(myidx, j + 2), s3 = __shfl(myidx, j + 3);
            float4 e0 = *(const float4*)(el + (size_t)s0 * 4);
            float4 e1 = *(const float4*)(el + (size_t)s1 * 4);
            float4 e2 = *(const float4*)(el + (size_t)s2 * 4);
            float4 e3 = *(const float4*)(el + (size_t)s3 * 4);
            half4 x0 = *(const half4*)(srcF + (size_t)s0 * 256 + lane * 4);
            half4 x1 = *(const half4*)(srcF + (size_t)s1 * 256 + lane * 4);
            half4 x2 = *(const half4*)(srcF + (size_t)s2 * 256 + lane * 4);
            half4 x3 = *(const half4*)(srcF + (size_t)s3 * 256 + lane * 4);
            float ev0[4] = {e0.x, e0.y, e0.z, e0.w};
            float ev1[4] = {e1.x, e1.y, e1.z, e1.w};
            float ev2[4] = {e2.x, e2.y, e2.z, e2.w};
            float ev3[4] = {e3.x, e3.y, e3.z, e3.w};
            float w0[4], w1[4], w2[4], w3[4];
#pragma unroll
            for (int h = 0; h < 4; ++h) {
                w0[h] = __expf(leaky(ev0[h] + erv[h]));
                w1[h] = __expf(leaky(ev1[h] + erv[h]));
                w2[h] = __expf(leaky(ev2[h] + erv[h]));
                w3[h] = __expf(leaky(ev3[h] + erv[h]));
                S[h] += (w0[h] + w1[h]) + (w2[h] + w3[h]);
            }
            float f0[4] = {(float)x0[0], (float)x0[1], (float)x0[2], (float)x0[3]};
            float f1[4] = {(float)x1[0], (float)x1[1], (float)x1[2], (float)x1[3]};
            float f2[4] = {(float)x2[0], (float)x2[1], (float)x2[2], (float)x2[3]};
            float f3[4] = {(float)x3[0], (float)x3[1], (float)x3[2], (float)x3[3]};
#pragma unroll
            for (int h = 0; h < 4; ++h)
#pragma unroll
                for (int e = 0; e < 4; ++e)
                    acc[h][e] += (w0[h] * f0[e] + w1[h] * f1[e])
                               + (w2[h] * f2[e] + w3[h] * f3[e]);
        }
        for (; j < nn; ++j) {
            int s = __shfl(myidx, j);
            float4 ea = *(const float4*)(el + (size_t)s * 4);
            half4 xa = *(const half4*)(srcF + (size_t)s * 256 + lane * 4);
            float eav[4] = {ea.x, ea.y, ea.z, ea.w};
            float wa[4];
#pragma unroll
            for (int h = 0; h < 4; ++h) {
                wa[h] = __expf(leaky(eav[h] + erv[h]));
                S[h] += wa[h];
            }
            float fa[4] = {(float)xa[0], (float)xa[1], (float)xa[2], (float)xa[3]};
#pragma unroll
            for (int h = 0; h < 4; ++h)
#pragma unroll
                for (int e = 0; e < 4; ++e)
                    acc[h][e] += wa[h] * fa[e];
        }
    }
#pragma unroll
    for (int h = 0; h < 4; ++h) {
        float inv = S[h] > 0.f ? 1.f / S[h] : 0.f;
        half4 o;
#pragma unroll
        for (int e = 0; e < 4; ++e) o[e] = (_Float16)(acc[h][e] * inv);
        *(half4*)(aggP + (size_t)h * PS + (size_t)d * 256 + lane * 4) = o;
    }
}

// ---------------- per-head wave-autonomous MFMA GEMM (r13 TRN epilogue) -----------
template <int NCOLS, int CV, bool RELU, bool F32OUT, bool TRN>
__global__ __launch_bounds__(512, 2) void gemmp(const _Float16* __restrict__ Aplanes,
        size_t APS, const _Float16* __restrict__ Bplanes, const float* __restrict__ bias,
        void* __restrict__ Z, int zstride, int M, int ntiles) {
    constexpr int NCF = NCOLS / 16;
    __shared__ __align__(16) _Float16 Bs[NCOLS * 256];
    __shared__ __align__(16) _Float16 Ts[TRN ? 8 * 16 * 72 : 8];
    const int t = threadIdx.x, l = t & 63, w = t >> 6;
    const int lr = l & 15, lh = l >> 4;
    const int hplane = blockIdx.y;
    const _Float16* Ah  = Aplanes + (size_t)hplane * APS;
    const _Float16* BtS = Bplanes + (size_t)hplane * NCOLS * 256;
    _Float16* Tw = &Ts[TRN ? w * 16 * 72 : 0];

    constexpr int BI = NCOLS / 16;
#pragma unroll
    for (int it = 0; it < BI; ++it) {
        int c = it * 512 + t;
        gload16(BtS + c * 8, (char*)Bs + c * 16);
    }
    __syncthreads();

    float bcol[NCF];
#pragma unroll
    for (int cf = 0; cf < NCF; ++cf) {
        int col = cf * 16 + lr;
        bcol[cf] = (col < CV) ? bias[hplane * CV + col] : 0.f;
    }

    const int NW = gridDim.x * 8;
    const int gw = blockIdx.x * 8 + w;

    half8 p0[8], p1[8];

    auto issue = [&](int tile, half8 (&p)[8]) {
        int row = tile * 16 + lr; if (row >= M) row = M - 1;
        const _Float16* ap = Ah + (size_t)row * 256 + lh * 8;
#pragma unroll
        for (int ks = 0; ks < 8; ++ks) p[ks] = *(const half8*)(ap + ks * 32);
        __builtin_amdgcn_sched_barrier(0);
    };

    auto compute = [&](int tile, half8 (&p)[8]) {
        f32x4 acc[NCF];
#pragma unroll
        for (int cf = 0; cf < NCF; ++cf) {
            acc[cf][0] = 0.f; acc[cf][1] = 0.f; acc[cf][2] = 0.f; acc[cf][3] = 0.f;
        }
#pragma unroll
        for (int ks = 0; ks < 8; ++ks) {
#pragma unroll
            for (int cf = 0; cf < NCF; ++cf) {
                int colr = cf * 16 + lr;
                half8 bf = *(const half8*)&Bs[colr * 256 +
                                              ((((ks * 4 + lh) ^ (colr & 31)) & 31) << 3)];
                acc[cf] = __builtin_amdgcn_mfma_f32_16x16x32_f16(p[ks], bf, acc[cf], 0, 0, 0);
            }
        }
        if constexpr (TRN) {
#pragma unroll
            for (int cf = 0; cf < NCF; ++cf) {
#pragma unroll
                for (int r = 0; r < 4; ++r) {
                    float v = acc[cf][r] + bcol[cf];
                    if constexpr (RELU) v = fmaxf(v, 0.f);
                    Tw[(lh * 4 + r) * 72 + cf * 16 + lr] = (_Float16)v;
                }
            }
#pragma unroll
            for (int i = 0; i < 2; ++i) {
                int trow = i * 8 + (l >> 3);
                half8 hv = *(const half8*)&Tw[trow * 72 + (l & 7) * 8];
                int node = tile * 16 + trow;
                if (node < M)
                    *(half8*)((_Float16*)Z + (size_t)node * zstride + hplane * NCOLS
                              + (l & 7) * 8) = hv;
            }
        } else {
#pragma unroll
            for (int cf = 0; cf < NCF; ++cf) {
                int col = cf * 16 + lr;
                if (col < CV) {
#pragma unroll
                    for (int r = 0; r < 4; ++r) {
                        int row = tile * 16 + lh * 4 + r;
                        if (row < M) {
                            float v = acc[cf][r] + bcol[cf];
                            if constexpr (RELU) v = fmaxf(v, 0.f);
                            if constexpr (F32OUT)
                                ((float*)Z)[(size_t)row * zstride + hplane * CV + col] = v;
                            else
                                ((_Float16*)Z)[(size_t)row * zstride + hplane * CV + col] =
                                    (_Float16)v;
                        }
                    }
                }
            }
        }
    };

    if (gw < ntiles) issue(gw, p0);
    for (int tt = gw; tt < ntiles; tt += 2 * NW) {
        int t1 = tt + NW;
        if (t1 < ntiles) {
            issue(t1, p1);
            asm volatile("s_waitcnt vmcnt(8)" ::: "memory");
        } else {
            asm volatile("s_waitcnt vmcnt(0)" ::: "memory");
        }
        compute(tt, p0);
        if (t1 < ntiles) {
            int t2 = tt + 2 * NW;
            if (t2 < ntiles) {
                issue(t2, p0);
                asm volatile("s_waitcnt vmcnt(8)" ::: "memory");
            } else {
                asm volatile("s_waitcnt vmcnt(0)" ::: "memory");
            }
            compute(t1, p1);
        }
    }
}

// combined histogram over both layers' edges
__global__ void hist2_k(const int* __restrict__ dst0, int E0,
                        const int* __restrict__ dst1, int E1, int* __restrict__ counts) {
    int i = blockIdx.x * blockDim.x + threadIdx.x;
    if (i < E0) atomicAdd(&counts[dst0[i]], 1);
    else if (i < E0 + E1) atomicAdd(&counts[ND0 + dst1[i - E0]], 1);
}

// ---- 3-kernel parallel exclusive scan ----
__global__ __launch_bounds__(256) void scan1_k(const int* __restrict__ counts, int n,
                                               int* __restrict__ part) {
    __shared__ int ws[4];
    int i = blockIdx.x * 256 + threadIdx.x;
    int lane = threadIdx.x & 63, wv = threadIdx.x >> 6;
    int s = (i < n) ? counts[i] : 0;
#pragma unroll
    for (int off = 32; off; off >>= 1) s += __shfl_xor(s, off);
    if (lane == 0) ws[wv] = s;
    __syncthreads();
    if (threadIdx.x == 0) part[blockIdx.x] = ws[0] + ws[1] + ws[2] + ws[3];
}

__global__ __launch_bounds__(256) void scan2_k(int* __restrict__ part, int nb) {
    __shared__ int ws[4];
    int tid = threadIdx.x, lane = tid & 63, wv = tid >> 6;
    int v = (tid < nb) ? part[tid] : 0;
    int x = v;
#pragma unroll
    for (int off = 1; off < 64; off <<= 1) {
        int u = __shfl_up(x, off);
        if (lane >= off) x += u;
    }
    if (lane == 63) ws[wv] = x;
    __syncthreads();
    int base = 0;
    for (int k = 0; k < wv; ++k) base += ws[k];
    if (tid < nb) part[tid] = base + x - v;
}

__global__ __launch_bounds__(256) void scan3_k(const int* __restrict__ counts, int n,
        const int* __restrict__ part, int* __restrict__ offsets, int* __restrict__ cursor) {
    __shared__ int ws[4];
    int i = blockIdx.x * 256 + threadIdx.x;
    int lane = threadIdx.x & 63, wv = threadIdx.x >> 6;
    int v = (i < n) ? counts[i] : 0;
    int x = v;
#pragma unroll
    for (int off = 1; off < 64; off <<= 1) {
        int u = __shfl_up(x, off);
        if (lane >= off) x += u;
    }
    if (lane == 63) ws[wv] = x;
    __syncthreads();
    int base = part[blockIdx.x];
    for (int k = 0; k < wv; ++k) base += ws[k];
    int off_ = base + x - v;
    if (i < n) { offsets[i] = off_; cursor[i] = off_; }
    if (i == n - 1) offsets[n] = off_ + v;
}

__global__ void scatter2_k(const int* __restrict__ src0, const int* __restrict__ dst0, int E0,
                           const int* __restrict__ src1, const int* __restrict__ dst1, int E1,
                           int* __restrict__ cursor, int* __restrict__ ssrc) {
    int i = blockIdx.x * blockDim.x + threadIdx.x;
    if (i < E0) {
        int p = atomicAdd(&cursor[dst0[i]], 1);
        ssrc[p] = src0[i];
    } else if (i < E0 + E1) {
        int j = i - E0;
        int p = atomicAdd(&cursor[ND0 + dst1[j]], 1);
        ssrc[p] = src1[j];
    }
}

// mean over heads + log_softmax; one wave per node (o1 f32 [*,188])
__global__ __launch_bounds__(256) void final_k(const float* __restrict__ o1,
        float* __restrict__ y, int n) {
    int wave = threadIdx.x >> 6, lane = threadIdx.x & 63;
    int node = blockIdx.x * 4 + wave;
    if (node >= n) return;
    const float* r = o1 + (size_t)node * HD1;
    float vv = 0.f, v = -INFINITY;
    if (lane < NCLS) {
        vv = 0.25f * (r[lane] + r[lane + NCLS] + r[lane + 2 * NCLS] + r[lane + 3 * NCLS]);
        v = vv;
    }
    float mx = v;
#pragma unroll
    for (int off = 32; off; off >>= 1) mx = fmaxf(mx, __shfl_xor(mx, off));
    float p = (lane < NCLS) ? __expf(vv - mx) : 0.f;
    float sum = p;
#pragma unroll
    for (int off = 32; off; off >>= 1) sum += __shfl_xor(sum, off);
    if (lane < NCLS) y[(size_t)node * NCLS + lane] = vv - mx - logf(sum);
}

extern "C" void kernel_launch(void* const* d_in, const int* in_sizes, int n_in,
                              void* d_out, int out_size, void* d_ws, size_t ws_size,
                              hipStream_t stream) {
    const float* x    = (const float*)d_in[0];
    const int*   src0 = (const int*)d_in[1];
    const int*   dst0 = (const int*)d_in[2];
    const int*   src1 = (const int*)d_in[3];
    const int*   dst1 = (const int*)d_in[4];
    const float* W0s  = (const float*)d_in[7];
    const float* W0d  = (const float*)d_in[8];
    const float* al0  = (const float*)d_in[9];
    const float* ar0  = (const float*)d_in[10];
    const float* b0   = (const float*)d_in[11];
    const float* W1s  = (const float*)d_in[12];
    const float* W1d  = (const float*)d_in[13];
    const float* al1  = (const float*)d_in[14];
    const float* ar1  = (const float*)d_in[15];
    const float* b1   = (const float*)d_in[16];
    const int E0 = in_sizes[1], E1 = in_sizes[3];
    const int NS0 = in_sizes[0] / IN;

    char* p = (char*)d_ws;
    auto take = [&](size_t bytes) {
        char* r = p;
        p += (bytes + 255) & ~(size_t)255;
        return r;
    };
    _Float16* xh    = (_Float16*)take((size_t)NS0 * 256 * 2);
    _Float16* aggP0 = (_Float16*)take((size_t)4 * ND0 * 256 * 2);
    _Float16* hbuf  = (_Float16*)take((size_t)ND0 * 256 * 2);
    _Float16* aggP1 = (_Float16*)take((size_t)4 * ND1 * 256 * 2);
    float*    o1    = (float*)take((size_t)ND1 * HD1 * 4);
    float*    el0   = (float*)take((size_t)NS0 * 4 * 4);
    float*    er0   = (float*)take((size_t)ND0 * 4 * 4);
    float*    el1   = (float*)take((size_t)ND0 * 4 * 4);
    float*    er1   = (float*)take((size_t)ND1 * 4 * 4);
    _Float16* B0p   = (_Float16*)take((size_t)4 * 64 * 256 * 2);
    _Float16* B1p   = (_Float16*)take((size_t)4 * 48 * 256 * 2);
    float*    vl0T  = (float*)take(4 * 256 * 4);
    float*    vr0T  = (float*)take(4 * 256 * 4);
    float*    vl1T  = (float*)take(4 * 256 * 4);
    float*    vr1T  = (float*)take(4 * 256 * 4);
    const int NDT = ND0 + ND1;
    int* counts = (int*)take((size_t)NDT * 4);
    int* offs   = (int*)take((size_t)(NDT + 1) * 4);
    int* cur    = (int*)take((size_t)NDT * 4);
    int* ss     = (int*)take((size_t)(E0 + E1) * 4);
    int* part   = (int*)take(256 * 4);

    const int NB = (NDT + 255) / 256;
    const int NT0 = (ND0 + 15) / 16, NT1 = (ND1 + 15) / 16;

    hipMemsetAsync(counts, 0, (size_t)NDT * 4, stream);

    prep_k<<<452, 256, 0, stream>>>(W0s, W1s, W0d, W1d, al0, ar0, al1, ar1,
                                    B0p, B1p, vl0T, vr0T, vl1T, vr1T);
    hist2_k<<<(E0 + E1 + 255) / 256, 256, 0, stream>>>(dst0, E0, dst1, E1, counts);
    scan1_k<<<NB, 256, 0, stream>>>(counts, NDT, part);
    scan2_k<<<1, 256, 0, stream>>>(part, NB);
    scan3_k<<<NB, 256, 0, stream>>>(counts, NDT, part, offs, cur);
    scatter2_k<<<(E0 + E1 + 255) / 256, 256, 0, stream>>>(src0, dst0, E0, src1, dst1, E1,
                                                          cur, ss);

    // ---- layer 0 ----
    lr_k<true, true><<<1024, 256, 0, stream>>>((const void*)x, vl0T, vr0T,
                                               xh, el0, er0, NS0, ND0);
    aggx<<<(ND0 + 3) / 4, 256, 0, stream>>>(ss, offs, 0, el0, er0, xh,
                                            aggP0, (size_t)ND0 * 256, ND0);
    gemmp<64, 64, true, false, true><<<dim3(128, 4), 512, 0, stream>>>(
        aggP0, (size_t)ND0 * 256, B0p, b0, (void*)hbuf, 256, ND0, NT0);

    // ---- layer 1 ----
    lr_k<false, false><<<512, 256, 0, stream>>>((const void*)hbuf, vl1T, vr1T,
                                                nullptr, el1, er1, ND0, ND1);
    aggx<<<(ND1 + 3) / 4, 256, 0, stream>>>(ss, offs, ND0, el1, er1, hbuf,
                                            aggP1, (size_t)ND1 * 256, ND1);
    gemmp<48, 47, false, true, false><<<dim3(32, 4), 512, 0, stream>>>(
        aggP1, (size_t)ND1 * 256, B1p, b1, (void*)o1, HD1, ND1, NT1);

    final_k<<<(ND1 + 3) / 4, 256, 0, stream>>>(o1, (float*)d_out, ND1);
}